// Round 1
// baseline (1470.490 us; speedup 1.0000x reference)
//
#include <hip/hip_runtime.h>
#include <cmath>

// ---------------------------------------------------------------------------
// PlainGNN: Q/K/V = x@W^T ; per-edge scores = leakyrelu(scale * sum_d D*(K_i-Q_j)^2)
// (self edges: K^T diag(D) Q) ; segment-softmax over destination row ;
// out[row] += alpha * V[col].
// N=100000, E=1600000, IN_F=128, HEADS=4, D_K=32.
// ---------------------------------------------------------------------------

#define HEADS 4
#define DK 32
#define FDIM 128

__device__ __forceinline__ void atomic_max_float(float* addr, float val) {
    // IEEE-754 trick: signed-int compare works for non-negative floats,
    // reversed unsigned compare for negative floats. smax init = -inf.
    if (val >= 0.0f) {
        atomicMax(reinterpret_cast<int*>(addr), __float_as_int(val));
    } else {
        atomicMin(reinterpret_cast<unsigned int*>(addr), __float_as_uint(val));
    }
}

__global__ __launch_bounds__(256) void init_buffers(
    float* __restrict__ out, float* __restrict__ smax, float* __restrict__ ssum,
    int n_out, int n_nh)
{
    int gid = blockIdx.x * 256 + threadIdx.x;
    if (gid < n_out) out[gid] = 0.0f;
    if (gid < n_nh) { smax[gid] = -__builtin_inff(); ssum[gid] = 0.0f; }
}

// Fused QKV projection. Block = 256 threads computes a 64-node x 128-out tile
// for one of {Wq,Wk,Wv} (blockIdx.y). k-tiles of 32 staged in LDS (+1 pad ->
// 2-way bank aliasing only, which is free on CDNA4).
__global__ __launch_bounds__(256) void qkv_gemm(
    const float* __restrict__ x, const float* __restrict__ Wq,
    const float* __restrict__ Wk, const float* __restrict__ Wv,
    float* __restrict__ Q, float* __restrict__ K, float* __restrict__ V, int N)
{
    __shared__ float xs[64][33];
    __shared__ float wsh[128][33];
    const float* __restrict__ W = (blockIdx.y == 0) ? Wq : (blockIdx.y == 1 ? Wk : Wv);
    float* __restrict__ O = (blockIdx.y == 0) ? Q : (blockIdx.y == 1 ? K : V);
    const int n0 = blockIdx.x * 64;
    const int tid = threadIdx.x;
    const int tn = (tid & 15) * 4;   // 4 consecutive nodes per thread
    const int to = (tid >> 4) * 8;   // 8 consecutive outputs per thread

    float acc[4][8];
#pragma unroll
    for (int i = 0; i < 4; ++i)
#pragma unroll
        for (int j = 0; j < 8; ++j) acc[i][j] = 0.0f;

    for (int kt = 0; kt < FDIM; kt += 32) {
#pragma unroll
        for (int idx = tid; idx < 64 * 32; idx += 256) {
            int r = idx >> 5, kk = idx & 31;
            int n = n0 + r;
            xs[r][kk] = (n < N) ? x[(size_t)n * FDIM + kt + kk] : 0.0f;
        }
#pragma unroll
        for (int idx = tid; idx < 128 * 32; idx += 256) {
            int r = idx >> 5, kk = idx & 31;
            wsh[r][kk] = W[r * FDIM + kt + kk];
        }
        __syncthreads();
#pragma unroll
        for (int k = 0; k < 32; ++k) {
            float xv[4], wv[8];
#pragma unroll
            for (int i = 0; i < 4; ++i) xv[i] = xs[tn + i][k];
#pragma unroll
            for (int j = 0; j < 8; ++j) wv[j] = wsh[to + j][k];
#pragma unroll
            for (int i = 0; i < 4; ++i)
#pragma unroll
                for (int j = 0; j < 8; ++j) acc[i][j] += xv[i] * wv[j];
        }
        __syncthreads();
    }

#pragma unroll
    for (int i = 0; i < 4; ++i) {
        int n = n0 + tn + i;
        if (n < N) {
#pragma unroll
            for (int j = 0; j < 8; ++j) O[(size_t)n * FDIM + to + j] = acc[i][j];
        }
    }
}

// One thread per (edge, head): 32-dim weighted dot, leaky-relu, atomic segment max.
__global__ __launch_bounds__(256) void edge_scores(
    const float* __restrict__ Q, const float* __restrict__ K,
    const float* __restrict__ D,
    const int* __restrict__ row, const int* __restrict__ col,
    float* __restrict__ score, float* __restrict__ smax,
    int E, int N)
{
    __shared__ float Dl[HEADS * DK];
    if (threadIdx.x < HEADS * DK) Dl[threadIdx.x] = D[threadIdx.x];
    __syncthreads();
    int gid = blockIdx.x * 256 + threadIdx.x;
    if (gid >= E * HEADS) return;
    int e = gid >> 2, h = gid & 3;
    int r = row[e], c = col[e];
    if ((unsigned)r >= (unsigned)N || (unsigned)c >= (unsigned)N) return;

    const float4* kp = reinterpret_cast<const float4*>(K + (size_t)r * FDIM + h * DK);
    const float4* qp = reinterpret_cast<const float4*>(Q + (size_t)c * FDIM + h * DK);
    const float4* dp = reinterpret_cast<const float4*>(Dl + h * DK);
    float s = 0.0f;
    if (r != c) {
#pragma unroll
        for (int i = 0; i < DK / 4; ++i) {
            float4 kv = kp[i], qv = qp[i], dv = dp[i];
            float dx = kv.x - qv.x, dy = kv.y - qv.y;
            float dz = kv.z - qv.z, dw = kv.w - qv.w;
            s += dv.x * dx * dx + dv.y * dy * dy + dv.z * dz * dz + dv.w * dw * dw;
        }
    } else {
#pragma unroll
        for (int i = 0; i < DK / 4; ++i) {
            float4 kv = kp[i], qv = qp[i], dv = dp[i];
            s += dv.x * kv.x * qv.x + dv.y * kv.y * qv.y
               + dv.z * kv.z * qv.z + dv.w * kv.w * qv.w;
        }
    }
    float z = s * 0.17677669529663687f;   // 1/sqrt(32)
    z = (z > 0.0f) ? z : 0.2f * z;        // leaky_relu slope 0.2
    score[gid] = z;
    atomic_max_float(&smax[r * HEADS + h], z);
}

// ex = exp(score - smax[row]); segment sum via atomics. Overwrites score with ex.
__global__ __launch_bounds__(256) void edge_expsum(
    const int* __restrict__ row, float* __restrict__ score,
    const float* __restrict__ smax, float* __restrict__ ssum, int E, int N)
{
    int gid = blockIdx.x * 256 + threadIdx.x;
    if (gid >= E * HEADS) return;
    int e = gid >> 2, h = gid & 3;
    int r = row[e];
    if ((unsigned)r >= (unsigned)N) return;
    float ex = __expf(score[gid] - smax[r * HEADS + h]);
    score[gid] = ex;
    atomicAdd(&ssum[r * HEADS + h], ex);
}

// 32 lanes per edge (one per d); each lane does 4 atomicAdds (one per head).
__global__ __launch_bounds__(256) void edge_aggregate(
    const int* __restrict__ row, const int* __restrict__ col,
    const float* __restrict__ score, const float* __restrict__ ssum,
    const float* __restrict__ V, float* __restrict__ out, int E, int N)
{
    int gid = blockIdx.x * 256 + threadIdx.x;
    if (gid >= E * 32) return;
    int e = gid >> 5, d = gid & 31;
    int r = row[e], c = col[e];
    if ((unsigned)r >= (unsigned)N || (unsigned)c >= (unsigned)N) return;
#pragma unroll
    for (int h = 0; h < HEADS; ++h) {
        float a = score[e * HEADS + h] / (ssum[r * HEADS + h] + 1e-16f);
        float v = V[(size_t)c * FDIM + h * DK + d];
        atomicAdd(&out[(size_t)r * FDIM + h * DK + d], a * v);
    }
}

extern "C" void kernel_launch(void* const* d_in, const int* in_sizes, int n_in,
                              void* d_out, int out_size, void* d_ws, size_t ws_size,
                              hipStream_t stream) {
    const float* x  = (const float*)d_in[0];
    const float* Wq = (const float*)d_in[1];
    const float* Wk = (const float*)d_in[2];
    const float* Wv = (const float*)d_in[3];
    const float* D  = (const float*)d_in[4];
    const int*  edge = (const int*)d_in[5];
    float* out = (float*)d_out;

    const int N = in_sizes[0] / FDIM;
    const int E = in_sizes[5] / 2;
    const int* row = edge;       // edge_index[0] = destination (segment id)
    const int* col = edge + E;   // edge_index[1] = source of Q_j / V

    // Workspace layout (floats): Q | K | V | score(E*H) | smax(N*H) | ssum(N*H)
    float* ws    = (float*)d_ws;
    float* Q     = ws;
    float* K     = Q + (size_t)N * FDIM;
    float* V     = K + (size_t)N * FDIM;
    float* score = V + (size_t)N * FDIM;
    float* smax  = score + (size_t)E * HEADS;
    float* ssum  = smax + (size_t)N * HEADS;

    const int n_out = N * FDIM;
    const int n_nh  = N * HEADS;

    init_buffers<<<(n_out + 255) / 256, 256, 0, stream>>>(out, smax, ssum, n_out, n_nh);

    dim3 ggrid((N + 63) / 64, 3);
    qkv_gemm<<<ggrid, 256, 0, stream>>>(x, Wq, Wk, Wv, Q, K, V, N);

    const int ne_h = E * HEADS;
    edge_scores<<<(ne_h + 255) / 256, 256, 0, stream>>>(Q, K, D, row, col, score, smax, E, N);
    edge_expsum<<<(ne_h + 255) / 256, 256, 0, stream>>>(row, score, smax, ssum, E, N);

    const int ne_d = E * 32;
    edge_aggregate<<<(ne_d + 255) / 256, 256, 0, stream>>>(row, col, score, ssum, V, out, E, N);
}

// Round 3
// 1228.033 us; speedup vs baseline: 1.1974x; 1.1974x over previous
//
#include <hip/hip_runtime.h>
#include <cmath>

// ---------------------------------------------------------------------------
// PlainGNN: Q/K/V = x@W^T ; per-edge scores = leakyrelu(scale * sum_d D*(K_i-Q_j)^2)
// (self edges: K^T diag(D) Q) ; segment-softmax over destination row ;
// out[row] += alpha * V[col].
// N=100000, E=1600000, IN_F=128, HEADS=4, D_K=32.
//
// R1: edge_aggregate was atomic-bound (204.8M device-scope atomicAdds, 819MB
// write-through, 640us). R2 builds a CSR by destination each launch and
// aggregates one wave per node with register accumulation — no output atomics.
// R3: fix aggregate_csr grid: one wave per node, 4 nodes/block -> ceil(N/4)
// blocks (R2 launched 392 blocks for 25000 needed -> 98% of out unwritten).
// ---------------------------------------------------------------------------

#define HEADS 4
#define DK 32
#define FDIM 128

__device__ __forceinline__ void atomic_max_float(float* addr, float val) {
    // IEEE-754 trick: signed-int compare for non-negative, reversed unsigned
    // compare for negative. smax init = -inf.
    if (val >= 0.0f) {
        atomicMax(reinterpret_cast<int*>(addr), __float_as_int(val));
    } else {
        atomicMin(reinterpret_cast<unsigned int*>(addr), __float_as_uint(val));
    }
}

// smax=-inf, ssum=0 over N*H ; deg=0, cursor=0 over N.
__global__ __launch_bounds__(256) void init_buffers(
    float* __restrict__ smax, float* __restrict__ ssum,
    int* __restrict__ deg, int* __restrict__ cursor, int n_nh, int n)
{
    int gid = blockIdx.x * 256 + threadIdx.x;
    if (gid < n_nh) { smax[gid] = -__builtin_inff(); ssum[gid] = 0.0f; }
    if (gid < n)    { deg[gid] = 0; cursor[gid] = 0; }
}

// Fused QKV projection. Block = 256 threads computes a 64-node x 128-out tile
// for one of {Wq,Wk,Wv} (blockIdx.y). k-tiles of 32 staged in LDS (+1 pad ->
// 2-way bank aliasing only, free on CDNA4).
__global__ __launch_bounds__(256) void qkv_gemm(
    const float* __restrict__ x, const float* __restrict__ Wq,
    const float* __restrict__ Wk, const float* __restrict__ Wv,
    float* __restrict__ Q, float* __restrict__ K, float* __restrict__ V, int N)
{
    __shared__ float xs[64][33];
    __shared__ float wsh[128][33];
    const float* __restrict__ W = (blockIdx.y == 0) ? Wq : (blockIdx.y == 1 ? Wk : Wv);
    float* __restrict__ O = (blockIdx.y == 0) ? Q : (blockIdx.y == 1 ? K : V);
    const int n0 = blockIdx.x * 64;
    const int tid = threadIdx.x;
    const int tn = (tid & 15) * 4;
    const int to = (tid >> 4) * 8;

    float acc[4][8];
#pragma unroll
    for (int i = 0; i < 4; ++i)
#pragma unroll
        for (int j = 0; j < 8; ++j) acc[i][j] = 0.0f;

    for (int kt = 0; kt < FDIM; kt += 32) {
#pragma unroll
        for (int idx = tid; idx < 64 * 32; idx += 256) {
            int r = idx >> 5, kk = idx & 31;
            int n = n0 + r;
            xs[r][kk] = (n < N) ? x[(size_t)n * FDIM + kt + kk] : 0.0f;
        }
#pragma unroll
        for (int idx = tid; idx < 128 * 32; idx += 256) {
            int r = idx >> 5, kk = idx & 31;
            wsh[r][kk] = W[r * FDIM + kt + kk];
        }
        __syncthreads();
#pragma unroll
        for (int k = 0; k < 32; ++k) {
            float xv[4], wv[8];
#pragma unroll
            for (int i = 0; i < 4; ++i) xv[i] = xs[tn + i][k];
#pragma unroll
            for (int j = 0; j < 8; ++j) wv[j] = wsh[to + j][k];
#pragma unroll
            for (int i = 0; i < 4; ++i)
#pragma unroll
                for (int j = 0; j < 8; ++j) acc[i][j] += xv[i] * wv[j];
        }
        __syncthreads();
    }

#pragma unroll
    for (int i = 0; i < 4; ++i) {
        int n = n0 + tn + i;
        if (n < N) {
#pragma unroll
            for (int j = 0; j < 8; ++j) O[(size_t)n * FDIM + to + j] = acc[i][j];
        }
    }
}

// One thread per (edge, head): 32-dim weighted dot, leaky-relu, atomic segment max.
__global__ __launch_bounds__(256) void edge_scores(
    const float* __restrict__ Q, const float* __restrict__ K,
    const float* __restrict__ D,
    const int* __restrict__ row, const int* __restrict__ col,
    float* __restrict__ score, float* __restrict__ smax,
    int E, int N)
{
    __shared__ float Dl[HEADS * DK];
    if (threadIdx.x < HEADS * DK) Dl[threadIdx.x] = D[threadIdx.x];
    __syncthreads();
    int gid = blockIdx.x * 256 + threadIdx.x;
    if (gid >= E * HEADS) return;
    int e = gid >> 2, h = gid & 3;
    int r = row[e], c = col[e];
    if ((unsigned)r >= (unsigned)N || (unsigned)c >= (unsigned)N) return;

    const float4* kp = reinterpret_cast<const float4*>(K + (size_t)r * FDIM + h * DK);
    const float4* qp = reinterpret_cast<const float4*>(Q + (size_t)c * FDIM + h * DK);
    const float4* dp = reinterpret_cast<const float4*>(Dl + h * DK);
    float s = 0.0f;
    if (r != c) {
#pragma unroll
        for (int i = 0; i < DK / 4; ++i) {
            float4 kv = kp[i], qv = qp[i], dv = dp[i];
            float dx = kv.x - qv.x, dy = kv.y - qv.y;
            float dz = kv.z - qv.z, dw = kv.w - qv.w;
            s += dv.x * dx * dx + dv.y * dy * dy + dv.z * dz * dz + dv.w * dw * dw;
        }
    } else {
#pragma unroll
        for (int i = 0; i < DK / 4; ++i) {
            float4 kv = kp[i], qv = qp[i], dv = dp[i];
            s += dv.x * kv.x * qv.x + dv.y * kv.y * qv.y
               + dv.z * kv.z * qv.z + dv.w * kv.w * qv.w;
        }
    }
    float z = s * 0.17677669529663687f;   // 1/sqrt(32)
    z = (z > 0.0f) ? z : 0.2f * z;        // leaky_relu slope 0.2
    score[gid] = z;
    atomic_max_float(&smax[r * HEADS + h], z);
}

// ex = exp(score - smax[row]); segment sum via atomics. Overwrites score with ex.
__global__ __launch_bounds__(256) void edge_expsum(
    const int* __restrict__ row, float* __restrict__ score,
    const float* __restrict__ smax, float* __restrict__ ssum, int E, int N)
{
    int gid = blockIdx.x * 256 + threadIdx.x;
    if (gid >= E * HEADS) return;
    int e = gid >> 2, h = gid & 3;
    int r = row[e];
    if ((unsigned)r >= (unsigned)N) return;
    float ex = __expf(score[gid] - smax[r * HEADS + h]);
    score[gid] = ex;
    atomicAdd(&ssum[r * HEADS + h], ex);
}

// ---- CSR build: degree histogram -> exclusive scan -> scatter fill ----

__global__ __launch_bounds__(256) void deg_count(
    const int* __restrict__ row, int* __restrict__ deg, int E, int N)
{
    int gid = blockIdx.x * 256 + threadIdx.x;
    if (gid >= E) return;
    int r = row[gid];
    if ((unsigned)r < (unsigned)N) atomicAdd(&deg[r], 1);
}

// Block-level exclusive scan over tiles of 1024 (256 thr x 4). Writes per-tile
// exclusive offsets into off[], per-tile totals into bsum[].
__global__ __launch_bounds__(256) void scan1(
    const int* __restrict__ deg, int* __restrict__ off, int* __restrict__ bsum, int N)
{
    __shared__ int lds[256];
    const int base = blockIdx.x * 1024;
    const int tid = threadIdx.x;
    int v[4];
    int tsum = 0;
#pragma unroll
    for (int i = 0; i < 4; ++i) {
        int idx = base + tid * 4 + i;
        v[i] = (idx < N) ? deg[idx] : 0;
        tsum += v[i];
    }
    lds[tid] = tsum;
    __syncthreads();
    for (int ofs = 1; ofs < 256; ofs <<= 1) {
        int t = (tid >= ofs) ? lds[tid - ofs] : 0;
        __syncthreads();
        lds[tid] += t;
        __syncthreads();
    }
    int run = lds[tid] - tsum;   // exclusive prefix of this thread within tile
    if (tid == 255) bsum[blockIdx.x] = lds[255];
#pragma unroll
    for (int i = 0; i < 4; ++i) {
        int idx = base + tid * 4 + i;
        if (idx < N) off[idx] = run;
        run += v[i];
    }
}

// Single-block exclusive scan of the per-tile totals (nb <= 256 required;
// N=100000 -> nb=98).
__global__ __launch_bounds__(256) void scan2(int* __restrict__ bsum, int nb)
{
    __shared__ int lds[256];
    int tid = threadIdx.x;
    int v = (tid < nb) ? bsum[tid] : 0;
    lds[tid] = v;
    __syncthreads();
    for (int ofs = 1; ofs < 256; ofs <<= 1) {
        int t = (tid >= ofs) ? lds[tid - ofs] : 0;
        __syncthreads();
        lds[tid] += t;
        __syncthreads();
    }
    if (tid < nb) bsum[tid] = lds[tid] - v;
}

__global__ __launch_bounds__(256) void scan3(
    int* __restrict__ off, const int* __restrict__ bsum, int N, int E)
{
    int gid = blockIdx.x * 256 + threadIdx.x;
    if (gid < N) off[gid] += bsum[gid >> 10];
    if (gid == 0) off[N] = E;
}

__global__ __launch_bounds__(256) void fill_csr(
    const int* __restrict__ row, const int* __restrict__ off,
    int* __restrict__ cursor, int* __restrict__ csr, int E, int N)
{
    int e = blockIdx.x * 256 + threadIdx.x;
    if (e >= E) return;
    int r = row[e];
    if ((unsigned)r >= (unsigned)N) return;
    int p = atomicAdd(&cursor[r], 1);
    csr[off[r] + p] = e;
}

// One wave per destination node. lane d-pair: dims (2*lane, 2*lane+1), head =
// lane>>4. Register accumulation over the node's CSR edge list, coalesced
// float2 store. No atomics.
__global__ __launch_bounds__(256) void aggregate_csr(
    const int* __restrict__ col, const int* __restrict__ off,
    const int* __restrict__ csr, const float* __restrict__ score,
    const float* __restrict__ ssum, const float* __restrict__ V,
    float* __restrict__ out, int N)
{
    int node = blockIdx.x * 4 + (threadIdx.x >> 6);
    if (node >= N) return;
    int lane = threadIdx.x & 63;
    int h = lane >> 4;                 // dims 2*lane..2*lane+1 lie in head lane>>4
    int d = lane * 2;
    float inv = 1.0f / (ssum[node * HEADS + h] + 1e-16f);
    int j0 = off[node], j1 = off[node + 1];
    float a0 = 0.0f, a1 = 0.0f;
    for (int j = j0; j < j1; ++j) {
        int e = csr[j];
        int c = col[e];
        float a = score[e * HEADS + h] * inv;
        const float2 v = *reinterpret_cast<const float2*>(V + (size_t)c * FDIM + d);
        a0 += a * v.x;
        a1 += a * v.y;
    }
    *reinterpret_cast<float2*>(out + (size_t)node * FDIM + d) = make_float2(a0, a1);
}

extern "C" void kernel_launch(void* const* d_in, const int* in_sizes, int n_in,
                              void* d_out, int out_size, void* d_ws, size_t ws_size,
                              hipStream_t stream) {
    const float* x  = (const float*)d_in[0];
    const float* Wq = (const float*)d_in[1];
    const float* Wk = (const float*)d_in[2];
    const float* Wv = (const float*)d_in[3];
    const float* D  = (const float*)d_in[4];
    const int*  edge = (const int*)d_in[5];
    float* out = (float*)d_out;

    const int N = in_sizes[0] / FDIM;
    const int E = in_sizes[5] / 2;
    const int* row = edge;       // edge_index[0] = destination (segment id)
    const int* col = edge + E;   // edge_index[1] = source of Q_j / V

    // Workspace layout: Q | K | V | score | smax | ssum | deg | cursor | off | bsum | csr
    float* ws    = (float*)d_ws;
    float* Q     = ws;
    float* K     = Q + (size_t)N * FDIM;
    float* V     = K + (size_t)N * FDIM;
    float* score = V + (size_t)N * FDIM;
    float* smax  = score + (size_t)E * HEADS;
    float* ssum  = smax + (size_t)N * HEADS;
    int* deg     = (int*)(ssum + (size_t)N * HEADS);
    int* cursor  = deg + N;
    int* off     = cursor + N;          // N+1 entries
    int* bsum    = off + (N + 1);       // up to 256 entries
    int* csr     = bsum + 256;          // E entries

    const int n_nh = N * HEADS;
    const int ne_h = E * HEADS;
    const int nb   = (N + 1023) / 1024;

    init_buffers<<<(n_nh + 255) / 256, 256, 0, stream>>>(smax, ssum, deg, cursor, n_nh, N);

    dim3 ggrid((N + 63) / 64, 3);
    qkv_gemm<<<ggrid, 256, 0, stream>>>(x, Wq, Wk, Wv, Q, K, V, N);

    // CSR build (independent of GEMM; overlaps via stream ordering anyway)
    deg_count<<<(E + 255) / 256, 256, 0, stream>>>(row, deg, E, N);
    scan1<<<nb, 256, 0, stream>>>(deg, off, bsum, N);
    scan2<<<1, 256, 0, stream>>>(bsum, nb);
    scan3<<<(N + 255) / 256, 256, 0, stream>>>(off, bsum, N, E);
    fill_csr<<<(E + 255) / 256, 256, 0, stream>>>(row, off, cursor, csr, E, N);

    edge_scores<<<(ne_h + 255) / 256, 256, 0, stream>>>(Q, K, D, row, col, score, smax, E, N);
    edge_expsum<<<(ne_h + 255) / 256, 256, 0, stream>>>(row, score, smax, ssum, E, N);

    aggregate_csr<<<(N + 3) / 4, 256, 0, stream>>>(
        col, off, csr, score, ssum, V, out, N);
}